// Round 6
// baseline (200.692 us; speedup 1.0000x reference)
//
#include <hip/hip_runtime.h>

// Problem constants (SubOut_60206851555968): B=8, U=E=1024, D=P=256, fp32 in/out.
#define BDIM 8
#define UDIM 1024
#define EDIM 1024
#define DDIM 256
#define PDIM 256

typedef __attribute__((ext_vector_type(8))) short bf16x8;   // 8 bf16 = 4 VGPRs
typedef __attribute__((ext_vector_type(4))) float f32x4;
typedef __attribute__((ext_vector_type(4))) unsigned short u16x4;

// s_waitcnt imm: vmcnt lo [3:0], expcnt [6:4]=7, lgkmcnt [11:8]=15, vmcnt hi [15:14]
#define WAIT_VM8  0x0F78   // vmcnt(8)
#define WAIT_VM0  0x0F70   // vmcnt(0)

__device__ __forceinline__ short f2bf(float x) {
    unsigned u = __float_as_uint(x);
    unsigned r = (u + 0x7FFFu + ((u >> 16) & 1u)) >> 16;   // RNE
    return (short)r;
}

__device__ __forceinline__ void dma16(const void* g, void* l) {
    __builtin_amdgcn_global_load_lds((const __attribute__((address_space(1))) void*)g,
                                     (__attribute__((address_space(3))) void*)l,
                                     16, 0, 0);
}

// ---------------------------------------------------------------------------
// prep: wT[n][k] = bf16(w[k][n]); zero row/col sums + d_out.
// ---------------------------------------------------------------------------
__global__ __launch_bounds__(256) void prep_kernel(
    const float* __restrict__ w, ushort* __restrict__ wT,
    float* __restrict__ sums, float* __restrict__ out, int out_size)
{
    int n = blockIdx.x, k = threadIdx.x;
    wT[(size_t)n * PDIM + k] = (ushort)f2bf(w[(size_t)k * PDIM + n]);
    int g = n * 256 + k;
    if (g < BDIM * UDIM + BDIM * EDIM) sums[g] = 0.f;
    if (g < out_size) out[g] = 0.f;
}

// ---------------------------------------------------------------------------
// proj: fat-wave version. 256 blocks; block = 64 rows x all 256 cols.
// A row (64 fp32/lane) loaded once into regs; 4 col-tiles of MFMA from
// L2-resident wT. Fewer, fatter waves -> less per-wave latency-chain overhead.
// ---------------------------------------------------------------------------
__global__ __launch_bounds__(256) void proj_kernel(
    const float* __restrict__ u_enc, const float* __restrict__ e_enc,
    const ushort* __restrict__ wT, const float* __restrict__ bias,
    ushort* __restrict__ u_p, ushort* __restrict__ e_p)
{
    int row0 = blockIdx.x * 64;              // 256 blocks cover 16384 rows
    const float* A; ushort* C;
    if (row0 < BDIM * UDIM) { A = u_enc; C = u_p; }
    else                    { A = e_enc; C = e_p; row0 -= BDIM * UDIM; }

    int tid  = threadIdx.x;
    int wave = tid >> 6, lane = tid & 63;
    int m = lane & 15, quad = lane >> 4;

    const float* aptr = A + (size_t)(row0 + wave * 16 + m) * DDIM + quad * 8;

    // Batch-load the whole A row, then convert once.
    float4 a[16];
    #pragma unroll
    for (int s = 0; s < 8; ++s) {
        a[2 * s]     = *(const float4*)(aptr + s * 32);
        a[2 * s + 1] = *(const float4*)(aptr + s * 32 + 4);
    }
    __builtin_amdgcn_sched_barrier(0);

    bf16x8 af[8];
    #pragma unroll
    for (int s = 0; s < 8; ++s) {
        float4 a0 = a[2 * s], a1 = a[2 * s + 1];
        af[s][0] = f2bf(a0.x); af[s][1] = f2bf(a0.y); af[s][2] = f2bf(a0.z); af[s][3] = f2bf(a0.w);
        af[s][4] = f2bf(a1.x); af[s][5] = f2bf(a1.y); af[s][6] = f2bf(a1.z); af[s][7] = f2bf(a1.w);
    }

    #pragma unroll
    for (int ct = 0; ct < 4; ++ct) {
        const ushort* bptr = wT + (size_t)(ct * 64 + m * 4) * DDIM + quad * 8;
        f32x4 acc[4] = {};
        #pragma unroll
        for (int ks = 0; ks < 8; ++ks) {
            #pragma unroll
            for (int nt = 0; nt < 4; ++nt) {
                bf16x8 bfr = *(const bf16x8*)(bptr + (size_t)nt * DDIM + ks * 32);
                acc[nt] = __builtin_amdgcn_mfma_f32_16x16x32_bf16(af[ks], bfr, acc[nt], 0, 0, 0);
            }
        }
        float4 bv = *(const float4*)&bias[ct * 64 + m * 4];
        #pragma unroll
        for (int r = 0; r < 4; ++r) {
            int row = row0 + wave * 16 + quad * 4 + r;
            u16x4 o;
            o[0] = (ushort)f2bf(acc[0][r] + bv.x);
            o[1] = (ushort)f2bf(acc[1][r] + bv.y);
            o[2] = (ushort)f2bf(acc[2][r] + bv.z);
            o[3] = (ushort)f2bf(acc[3][r] + bv.w);
            *(u16x4*)&C[(size_t)row * PDIM + ct * 64 + m * 4] = o;
        }
    }
}

// ---------------------------------------------------------------------------
// fused (m97-style): grid 256 blocks = (b, iu, eh); block owns u-strip 64 x
// e-half 512 = 8 tiles of 64x64. A-frags in regs. e_p tiles DMA'd into 2x32KB
// LDS (global_load_lds, XOR k-swizzle for conflict-free ds_read_b128).
// pair/mask prefetched 1 tile ahead into regs, issued before the DMA so the
// manual vmcnt(8) wait (leave next DMA in flight) drains them under compute.
// ---------------------------------------------------------------------------
__global__ __launch_bounds__(256) void fused_kernel(
    const ushort* __restrict__ u_p, const ushort* __restrict__ e_p,
    const float* __restrict__ pair_enc, const float* __restrict__ ue_mask,
    const float* __restrict__ bpp_w_p, const float* __restrict__ bpp_b_p,
    float* __restrict__ row_sums, float* __restrict__ col_sums)
{
    __shared__ __align__(16) ushort ep_lds[2][64 * 256];   // 2 x 32 KB

    int bx = blockIdx.x;               // 256 blocks
    int b  = bx >> 5;
    int iu = (bx >> 1) & 15;
    int eh = bx & 1;
    int u0 = iu * 64;
    int ebase = eh * 512;

    int tid  = threadIdx.x;
    int wave = tid >> 6, lane = tid & 63;
    int m = lane & 15, quad = lane >> 4;
    int half = lane >> 5, slot = lane & 31;   // DMA lane decomposition

    const ushort* upb = u_p + (size_t)b * UDIM * PDIM;
    const ushort* epb = e_p + (size_t)b * EDIM * PDIM;
    const float*  pm  = pair_enc + (size_t)b * UDIM * EDIM;
    const float*  mm  = ue_mask  + (size_t)b * UDIM * EDIM;

    // A-frags: u_p strip rows, kept in registers for all 8 tiles.
    bf16x8 af[8];
    {
        const ushort* au = upb + (size_t)(u0 + wave * 16 + m) * PDIM + quad * 8;
        #pragma unroll
        for (int s = 0; s < 8; ++s) af[s] = *(const bf16x8*)(au + s * 32);
    }

    int prow = u0 + wave * 16 + quad * 4;
    float4 pvr[2][4], mvr[2][4];

    // Prologue: pair/mask(0) regs, then DMA e_p tile 0 into buf 0.
    #pragma unroll
    for (int r = 0; r < 4; ++r) {
        size_t idx = (size_t)(prow + r) * EDIM + ebase + m * 4;
        mvr[0][r] = *(const float4*)&mm[idx];
        pvr[0][r] = *(const float4*)&pm[idx];
    }
    #pragma unroll
    for (int j = 0; j < 8; ++j) {
        int lr = 16 * wave + 2 * j + half;                    // local e-row 0..63
        int kseg = slot ^ ((lr >> 2) & 7);                    // XOR swizzle
        const ushort* g = epb + (size_t)(ebase + lr) * PDIM + kseg * 8;
        dma16(g, &ep_lds[0][(16 * wave + 2 * j) * 256]);      // +lane*16 implicit
    }

    float bw = bpp_w_p[0], bb = bpp_b_p[0];

    #pragma unroll
    for (int t = 0; t < 8; ++t) {
        int cb = t & 1, nb = cb ^ 1;

        if (t < 7) {
            // pair/mask(t+1) first (drained by the wait), DMA(t+1) last (stays in flight).
            #pragma unroll
            for (int r = 0; r < 4; ++r) {
                size_t idx = (size_t)(prow + r) * EDIM + ebase + (t + 1) * 64 + m * 4;
                mvr[nb][r] = *(const float4*)&mm[idx];
                pvr[nb][r] = *(const float4*)&pm[idx];
            }
            #pragma unroll
            for (int j = 0; j < 8; ++j) {
                int lr = 16 * wave + 2 * j + half;
                int kseg = slot ^ ((lr >> 2) & 7);
                const ushort* g = epb + (size_t)(ebase + (t + 1) * 64 + lr) * PDIM + kseg * 8;
                dma16(g, &ep_lds[nb][(16 * wave + 2 * j) * 256]);
            }
            __builtin_amdgcn_s_waitcnt(WAIT_VM8);   // ep(t) done; ep(t+1) still in flight
        } else {
            __builtin_amdgcn_s_waitcnt(WAIT_VM0);
        }
        __builtin_amdgcn_s_barrier();               // buf[cb] visible to all waves
        __builtin_amdgcn_sched_barrier(0);

        // K-loop: pure LDS + MFMA, no vmem waits.
        f32x4 acc[4] = {};
        #pragma unroll
        for (int ks = 0; ks < 8; ++ks) {
            #pragma unroll
            for (int nt = 0; nt < 4; ++nt) {
                int row = m * 4 + nt;
                int sl  = (ks * 4 + quad) ^ (m & 7);
                bf16x8 bfr = *(const bf16x8*)&ep_lds[cb][row * 256 + sl * 8];
                acc[nt] = __builtin_amdgcn_mfma_f32_16x16x32_bf16(af[ks], bfr, acc[nt], 0, 0, 0);
            }
        }
        __builtin_amdgcn_s_barrier();               // all reads of buf[cb] done

        // Epilogue: gate + reductions (no LDS, no __syncthreads).
        float rsum[4];
        float csum[4] = {0.f, 0.f, 0.f, 0.f};
        #pragma unroll
        for (int r = 0; r < 4; ++r) {
            float mvv[4] = {mvr[cb][r].x, mvr[cb][r].y, mvr[cb][r].z, mvr[cb][r].w};
            float pvv[4] = {pvr[cb][r].x, pvr[cb][r].y, pvr[cb][r].z, pvr[cb][r].w};
            float rs = 0.f;
            #pragma unroll
            for (int nt = 0; nt < 4; ++nt) {
                float arg = bw * pvv[nt] + bb + mvv[nt] * acc[nt][r];
                float s = mvv[nt] / (1.f + __expf(-arg));
                rs       += s;
                csum[nt] += s;
            }
            rsum[r] = rs;
        }

        // Row sums: reduce across 16 m-lanes; quad leaders atomic.
        #pragma unroll
        for (int r = 0; r < 4; ++r) {
            float v = rsum[r];
            v += __shfl_xor(v, 1); v += __shfl_xor(v, 2);
            v += __shfl_xor(v, 4); v += __shfl_xor(v, 8);
            if (m == 0)
                atomicAdd(&row_sums[(size_t)b * UDIM + prow + r], v);
        }
        // Col sums: reduce across quads; quad-0 lanes atomic (per wave).
        #pragma unroll
        for (int nt = 0; nt < 4; ++nt) {
            float v = csum[nt];
            v += __shfl_xor(v, 16); v += __shfl_xor(v, 32);
            if (quad == 0)
                atomicAdd(&col_sums[(size_t)b * EDIM + ebase + t * 64 + m * 4 + nt], v);
        }
    }
}

// ---------------------------------------------------------------------------
// finish: out[b,0:256] = row_sums[b,:]@u_enc[b]; out[b,256:512] = col_sums@e_enc.
// grid (B,2,32): 32 rows/block, 8 independent accumulator chains; row scalars
// are block-uniform (s_load).
// ---------------------------------------------------------------------------
__global__ __launch_bounds__(256) void finish_kernel(
    const float* __restrict__ u_enc, const float* __restrict__ e_enc,
    const float* __restrict__ row_sums, const float* __restrict__ col_sums,
    float* __restrict__ out)
{
    int b = blockIdx.x;
    int half = blockIdx.y;
    int chunk = blockIdx.z;          // 32 chunks of 32 rows
    int d = threadIdx.x;

    const float* enc = half ? e_enc : u_enc;
    const float* s   = half ? col_sums : row_sums;

    int base = chunk * 32;
    float sv[32];
    #pragma unroll
    for (int u = 0; u < 32; ++u) sv[u] = s[(size_t)b * UDIM + base + u];

    float a[8] = {};
    #pragma unroll
    for (int u0 = 0; u0 < 4; ++u0) {
        #pragma unroll
        for (int j = 0; j < 8; ++j) {
            int u = u0 * 8 + j;
            a[j] += sv[u] * enc[(size_t)(b * UDIM + base + u) * DDIM + d];
        }
    }
    float acc = ((a[0] + a[1]) + (a[2] + a[3])) + ((a[4] + a[5]) + (a[6] + a[7]));
    atomicAdd(&out[(size_t)b * 2 * DDIM + half * DDIM + d], acc);
}

// ---------------------------------------------------------------------------
extern "C" void kernel_launch(void* const* d_in, const int* in_sizes, int n_in,
                              void* d_out, int out_size, void* d_ws, size_t ws_size,
                              hipStream_t stream)
{
    const float* u_enc    = (const float*)d_in[0];
    const float* e_enc    = (const float*)d_in[1];
    const float* pair_enc = (const float*)d_in[2];
    const float* ue_mask  = (const float*)d_in[3];
    const float* w_kernel = (const float*)d_in[4];
    const float* w_bias   = (const float*)d_in[5];
    const float* bpp_w    = (const float*)d_in[6];
    const float* bpp_b    = (const float*)d_in[7];
    float* out = (float*)d_out;

    // ws layout: u_p bf16 (4MB) | e_p bf16 (4MB) | wT bf16 (128KB) | sums fp32 (64KB)
    ushort* u_p = (ushort*)d_ws;
    ushort* e_p = u_p + (size_t)BDIM * UDIM * PDIM;
    ushort* wT  = e_p + (size_t)BDIM * EDIM * PDIM;
    float* row_sums = (float*)(wT + (size_t)DDIM * PDIM);
    float* col_sums = row_sums + BDIM * UDIM;

    prep_kernel<<<dim3(256), 256, 0, stream>>>(w_kernel, wT, row_sums, out, out_size);

    proj_kernel<<<dim3(256), 256, 0, stream>>>(u_enc, e_enc, wT, w_bias, u_p, e_p);

    fused_kernel<<<dim3(256), 256, 0, stream>>>(u_p, e_p, pair_enc, ue_mask,
                                                bpp_w, bpp_b, row_sums, col_sums);

    finish_kernel<<<dim3(BDIM, 2, 32), 256, 0, stream>>>(u_enc, e_enc, row_sums, col_sums, out);
}

// Round 7
// 198.795 us; speedup vs baseline: 1.0095x; 1.0095x over previous
//
#include <hip/hip_runtime.h>

// Problem constants (SubOut_60206851555968): B=8, U=E=1024, D=P=256, fp32 in/out.
#define BDIM 8
#define UDIM 1024
#define EDIM 1024
#define DDIM 256
#define PDIM 256

typedef __attribute__((ext_vector_type(8))) short bf16x8;   // 8 bf16 = 4 VGPRs
typedef __attribute__((ext_vector_type(4))) float f32x4;
typedef __attribute__((ext_vector_type(4))) unsigned short u16x4;

__device__ __forceinline__ short f2bf(float x) {
    unsigned u = __float_as_uint(x);
    unsigned r = (u + 0x7FFFu + ((u >> 16) & 1u)) >> 16;   // RNE
    return (short)r;
}
__device__ __forceinline__ float bf2f(unsigned short h) {
    return __uint_as_float(((unsigned)h) << 16);
}

// ---------------------------------------------------------------------------
// prep: wT[n][k] = bf16(w[k][n]); zero row/col sums + d_out.
// ---------------------------------------------------------------------------
__global__ __launch_bounds__(256) void prep_kernel(
    const float* __restrict__ w, ushort* __restrict__ wT,
    float* __restrict__ sums, float* __restrict__ out, int out_size)
{
    int n = blockIdx.x, k = threadIdx.x;
    wT[(size_t)n * PDIM + k] = (ushort)f2bf(w[(size_t)k * PDIM + n]);
    int g = n * 256 + k;
    if (g < BDIM * UDIM + BDIM * EDIM) sums[g] = 0.f;
    if (g < out_size) out[g] = 0.f;
}

// ---------------------------------------------------------------------------
// proj: u_p/e_p = bf16(enc @ w + bias). MFMA 16x16x32, grid (256,4) = 1024
// blocks of 64x64. Col-permuted B (physical col m*4+nt) -> ushort4 stores.
// ---------------------------------------------------------------------------
__global__ __launch_bounds__(256) void proj_kernel(
    const float* __restrict__ u_enc, const float* __restrict__ e_enc,
    const ushort* __restrict__ wT, const float* __restrict__ bias,
    ushort* __restrict__ u_p, ushort* __restrict__ e_p)
{
    int row0 = blockIdx.x * 64;
    int col0 = blockIdx.y * 64;
    const float* A; ushort* C;
    if (row0 < BDIM * UDIM) { A = u_enc; C = u_p; }
    else                    { A = e_enc; C = e_p; row0 -= BDIM * UDIM; }

    int tid  = threadIdx.x;
    int wave = tid >> 6, lane = tid & 63;
    int m = lane & 15, quad = lane >> 4;

    const float*  aptr = A + (size_t)(row0 + wave * 16 + m) * DDIM + quad * 8;
    const ushort* bptr = wT + (size_t)(col0 + m * 4) * DDIM + quad * 8;

    float4 a[16];
    #pragma unroll
    for (int s = 0; s < 8; ++s) {
        a[2 * s]     = *(const float4*)(aptr + s * 32);
        a[2 * s + 1] = *(const float4*)(aptr + s * 32 + 4);
    }

    f32x4 acc[4] = {};
    #pragma unroll
    for (int s = 0; s < 8; ++s) {
        float4 a0 = a[2 * s], a1 = a[2 * s + 1];
        bf16x8 af;
        af[0] = f2bf(a0.x); af[1] = f2bf(a0.y); af[2] = f2bf(a0.z); af[3] = f2bf(a0.w);
        af[4] = f2bf(a1.x); af[5] = f2bf(a1.y); af[6] = f2bf(a1.z); af[7] = f2bf(a1.w);
        #pragma unroll
        for (int nt = 0; nt < 4; ++nt) {
            bf16x8 bfr = *(const bf16x8*)(bptr + (size_t)nt * DDIM + s * 32);
            acc[nt] = __builtin_amdgcn_mfma_f32_16x16x32_bf16(af, bfr, acc[nt], 0, 0, 0);
        }
    }

    // acc[nt][r]: row = wave*16 + quad*4 + r, col = col0 + m*4 + nt.
    float4 bv = *(const float4*)&bias[col0 + m * 4];
    #pragma unroll
    for (int r = 0; r < 4; ++r) {
        int row = row0 + wave * 16 + quad * 4 + r;
        u16x4 o;
        o[0] = (ushort)f2bf(acc[0][r] + bv.x);
        o[1] = (ushort)f2bf(acc[1][r] + bv.y);
        o[2] = (ushort)f2bf(acc[2][r] + bv.z);
        o[3] = (ushort)f2bf(acc[3][r] + bv.w);
        *(u16x4*)&C[(size_t)row * PDIM + col0 + m * 4] = o;
    }
}

// ---------------------------------------------------------------------------
// op_gemm: op[b,u,e] = u_p[b,u,:] . e_p[b,e,:] (bf16 out, 16 MB). Pure GEMM,
// 64x64 tiles, grid (256, 8). Col-permuted B -> coalesced ushort4 stores.
// ---------------------------------------------------------------------------
__global__ __launch_bounds__(256) void op_gemm_kernel(
    const ushort* __restrict__ u_p, const ushort* __restrict__ e_p,
    ushort* __restrict__ op)
{
    int b  = blockIdx.y;
    int iu = blockIdx.x >> 4, ie = blockIdx.x & 15;
    int u0 = iu * 64, e0 = ie * 64;

    int tid  = threadIdx.x;
    int wave = tid >> 6, lane = tid & 63;
    int m = lane & 15, quad = lane >> 4;

    const ushort* Au = u_p + (size_t)b * UDIM * PDIM + (size_t)(u0 + wave * 16 + m) * PDIM + quad * 8;
    const ushort* Be = e_p + (size_t)b * EDIM * PDIM + (size_t)(e0 + m * 4) * PDIM + quad * 8;

    f32x4 acc[4] = {};
    #pragma unroll
    for (int k0 = 0; k0 < PDIM; k0 += 32) {
        bf16x8 af = *(const bf16x8*)(Au + k0);
        #pragma unroll
        for (int nt = 0; nt < 4; ++nt) {
            bf16x8 bfr = *(const bf16x8*)(Be + (size_t)nt * PDIM + k0);   // phys col m*4+nt
            acc[nt] = __builtin_amdgcn_mfma_f32_16x16x32_bf16(af, bfr, acc[nt], 0, 0, 0);
        }
    }

    // D[row=quad*4+r][col=m] of tile nt -> e = e0 + m*4 + nt (linear ushort4).
    ushort* ob = op + (size_t)b * UDIM * EDIM;
    #pragma unroll
    for (int r = 0; r < 4; ++r) {
        int row = u0 + wave * 16 + quad * 4 + r;
        u16x4 o;
        o[0] = (ushort)f2bf(acc[0][r]);
        o[1] = (ushort)f2bf(acc[1][r]);
        o[2] = (ushort)f2bf(acc[2][r]);
        o[3] = (ushort)f2bf(acc[3][r]);
        *(u16x4*)&ob[(size_t)row * EDIM + e0 + m * 4] = o;
    }
}

// ---------------------------------------------------------------------------
// stream: the pure-BW gate pass. grid (64, 8): block = 16 full rows of one
// batch. Thread t owns e = 4t..4t+3 for every row. No LDS, no syncthreads.
//   s = mask * sigmoid(bw*pair + bb + mask*op)
//   row_sums[b,u] += sum_e s   (wave shuffle + 4 atomics/row)
//   col_sums[b,e] += sum_u s   (per-thread accumulators, 4 atomics at end)
// ---------------------------------------------------------------------------
__global__ __launch_bounds__(256) void stream_kernel(
    const ushort* __restrict__ op, const float* __restrict__ pair_enc,
    const float* __restrict__ ue_mask,
    const float* __restrict__ bpp_w_p, const float* __restrict__ bpp_b_p,
    float* __restrict__ row_sums, float* __restrict__ col_sums)
{
    int b = blockIdx.y;
    int row0 = blockIdx.x * 16;
    int t = threadIdx.x;
    int lane = t & 63;
    int e4 = t * 4;

    const float*  pm = pair_enc + (size_t)b * UDIM * EDIM;
    const float*  mm = ue_mask  + (size_t)b * UDIM * EDIM;
    const ushort* ob = op       + (size_t)b * UDIM * EDIM;
    float bw = bpp_w_p[0], bb = bpp_b_p[0];

    float cs0 = 0.f, cs1 = 0.f, cs2 = 0.f, cs3 = 0.f;

    #pragma unroll 2
    for (int r = 0; r < 16; r += 2) {
        size_t i0 = (size_t)(row0 + r) * EDIM + e4;
        size_t i1 = i0 + EDIM;
        // Issue all 6 vector loads for both rows before any compute.
        float4 p0 = *(const float4*)&pm[i0];
        float4 k0 = *(const float4*)&mm[i0];
        u16x4  o0 = *(const u16x4*)&ob[i0];
        float4 p1 = *(const float4*)&pm[i1];
        float4 k1 = *(const float4*)&mm[i1];
        u16x4  o1 = *(const u16x4*)&ob[i1];

        float pa[8] = {p0.x, p0.y, p0.z, p0.w, p1.x, p1.y, p1.z, p1.w};
        float ka[8] = {k0.x, k0.y, k0.z, k0.w, k1.x, k1.y, k1.z, k1.w};
        float oa[8] = {bf2f(o0[0]), bf2f(o0[1]), bf2f(o0[2]), bf2f(o0[3]),
                       bf2f(o1[0]), bf2f(o1[1]), bf2f(o1[2]), bf2f(o1[3])};

        float s[8];
        #pragma unroll
        for (int j = 0; j < 8; ++j) {
            float arg = bw * pa[j] + bb + ka[j] * oa[j];
            s[j] = ka[j] / (1.f + __expf(-arg));
        }
        cs0 += s[0] + s[4]; cs1 += s[1] + s[5];
        cs2 += s[2] + s[6]; cs3 += s[3] + s[7];

        float rs0 = (s[0] + s[1]) + (s[2] + s[3]);
        float rs1 = (s[4] + s[5]) + (s[6] + s[7]);
        rs0 += __shfl_xor(rs0, 1);  rs1 += __shfl_xor(rs1, 1);
        rs0 += __shfl_xor(rs0, 2);  rs1 += __shfl_xor(rs1, 2);
        rs0 += __shfl_xor(rs0, 4);  rs1 += __shfl_xor(rs1, 4);
        rs0 += __shfl_xor(rs0, 8);  rs1 += __shfl_xor(rs1, 8);
        rs0 += __shfl_xor(rs0, 16); rs1 += __shfl_xor(rs1, 16);
        rs0 += __shfl_xor(rs0, 32); rs1 += __shfl_xor(rs1, 32);
        if (lane == 0) {
            atomicAdd(&row_sums[(size_t)b * UDIM + row0 + r],     rs0);
            atomicAdd(&row_sums[(size_t)b * UDIM + row0 + r + 1], rs1);
        }
    }

    atomicAdd(&col_sums[(size_t)b * EDIM + e4 + 0], cs0);
    atomicAdd(&col_sums[(size_t)b * EDIM + e4 + 1], cs1);
    atomicAdd(&col_sums[(size_t)b * EDIM + e4 + 2], cs2);
    atomicAdd(&col_sums[(size_t)b * EDIM + e4 + 3], cs3);
}

// ---------------------------------------------------------------------------
// finish: out[b,0:256] = row_sums[b,:]@u_enc[b]; out[b,256:512] = col_sums@e_enc.
// grid (B,2,32): 32 rows/block, 8 independent accumulator chains.
// ---------------------------------------------------------------------------
__global__ __launch_bounds__(256) void finish_kernel(
    const float* __restrict__ u_enc, const float* __restrict__ e_enc,
    const float* __restrict__ row_sums, const float* __restrict__ col_sums,
    float* __restrict__ out)
{
    int b = blockIdx.x;
    int half = blockIdx.y;
    int chunk = blockIdx.z;          // 32 chunks of 32 rows
    int d = threadIdx.x;

    const float* enc = half ? e_enc : u_enc;
    const float* s   = half ? col_sums : row_sums;

    int base = chunk * 32;
    float sv[32];
    #pragma unroll
    for (int u = 0; u < 32; ++u) sv[u] = s[(size_t)b * UDIM + base + u];

    float a[8] = {};
    #pragma unroll
    for (int u0 = 0; u0 < 4; ++u0) {
        #pragma unroll
        for (int j = 0; j < 8; ++j) {
            int u = u0 * 8 + j;
            a[j] += sv[u] * enc[(size_t)(b * UDIM + base + u) * DDIM + d];
        }
    }
    float acc = ((a[0] + a[1]) + (a[2] + a[3])) + ((a[4] + a[5]) + (a[6] + a[7]));
    atomicAdd(&out[(size_t)b * 2 * DDIM + half * DDIM + d], acc);
}

// ---------------------------------------------------------------------------
extern "C" void kernel_launch(void* const* d_in, const int* in_sizes, int n_in,
                              void* d_out, int out_size, void* d_ws, size_t ws_size,
                              hipStream_t stream)
{
    const float* u_enc    = (const float*)d_in[0];
    const float* e_enc    = (const float*)d_in[1];
    const float* pair_enc = (const float*)d_in[2];
    const float* ue_mask  = (const float*)d_in[3];
    const float* w_kernel = (const float*)d_in[4];
    const float* w_bias   = (const float*)d_in[5];
    const float* bpp_w    = (const float*)d_in[6];
    const float* bpp_b    = (const float*)d_in[7];
    float* out = (float*)d_out;

    // ws: u_p bf16 4MB | e_p bf16 4MB | op bf16 16MB | wT bf16 128KB | sums 64KB
    ushort* u_p = (ushort*)d_ws;
    ushort* e_p = u_p + (size_t)BDIM * UDIM * PDIM;
    ushort* op  = e_p + (size_t)BDIM * EDIM * PDIM;
    ushort* wT  = op  + (size_t)BDIM * UDIM * EDIM;
    float* row_sums = (float*)(wT + (size_t)DDIM * PDIM);
    float* col_sums = row_sums + BDIM * UDIM;

    prep_kernel<<<dim3(256), 256, 0, stream>>>(w_kernel, wT, row_sums, out, out_size);

    proj_kernel<<<dim3(256, 4), 256, 0, stream>>>(u_enc, e_enc, wT, w_bias, u_p, e_p);

    op_gemm_kernel<<<dim3(256, BDIM), 256, 0, stream>>>(u_p, e_p, op);

    stream_kernel<<<dim3(64, BDIM), 256, 0, stream>>>(op, pair_enc, ue_mask,
                                                      bpp_w, bpp_b, row_sums, col_sums);

    finish_kernel<<<dim3(BDIM, 2, 32), 256, 0, stream>>>(u_enc, e_enc, row_sums, col_sums, out);
}